// Round 10
// baseline (155.236 us; speedup 1.0000x reference)
//
#include <hip/hip_runtime.h>
#include <hip/hip_bf16.h>

typedef __attribute__((ext_vector_type(8))) short short8;
typedef __attribute__((ext_vector_type(4))) float f32x4;

#define OUT_DIM 11008
#define IN_DIM  4096
#define B_DIM   32
#define KSPL    16
#define KPB     (IN_DIM / KSPL)        // 256 k per split-K block
#define PART_ELEMS (B_DIM * OUT_DIM)   // 352256 elems per partial slice
#define NTILES  (OUT_DIM / 256)        // 43
#define CNT_OFF ((size_t)KSPL * PART_ELEMS * 2)   // counters after partials

__device__ __forceinline__ short8 cvt8(const float* __restrict__ src) {
  f32x4 f0 = *reinterpret_cast<const f32x4*>(src);
  f32x4 f1 = *reinterpret_cast<const f32x4*>(src + 4);
  short8 v;
  __hip_bfloat16 h;
  h = __float2bfloat16(f0[0]); v[0] = *reinterpret_cast<short*>(&h);
  h = __float2bfloat16(f0[1]); v[1] = *reinterpret_cast<short*>(&h);
  h = __float2bfloat16(f0[2]); v[2] = *reinterpret_cast<short*>(&h);
  h = __float2bfloat16(f0[3]); v[3] = *reinterpret_cast<short*>(&h);
  h = __float2bfloat16(f1[0]); v[4] = *reinterpret_cast<short*>(&h);
  h = __float2bfloat16(f1[1]); v[5] = *reinterpret_cast<short*>(&h);
  h = __float2bfloat16(f1[2]); v[6] = *reinterpret_cast<short*>(&h);
  h = __float2bfloat16(f1[3]); v[7] = *reinterpret_cast<short*>(&h);
  return v;
}

// R9 hot loop byte-identical (39.85us). ONE change: fused split-K reduce via
// per-N-tile semaphore — last-arriving block reduces the 16 bf16 partial
// slices for its tile and writes y (scale applied). No second dispatch.
__global__ __launch_bounds__(256, 4)
void bitnet_fused(const float* __restrict__ x,
                  const float* __restrict__ w,
                  const float* __restrict__ scale,
                  unsigned short* __restrict__ ws,
                  unsigned int* __restrict__ cnt,
                  float* __restrict__ y)
{
  __shared__ short xl[8][2][64 * 8];   // 16 KB: bf16 A-fragments, staged once
  __shared__ unsigned int sOld;

  const int tid  = threadIdx.x;
  const int lane = tid & 63;
  const int wv   = tid >> 6;       // wave 0..3
  const int l15  = lane & 15;
  const int lg   = lane >> 4;      // 0..3
  const int obase = blockIdx.x * 256;
  const int ow    = obase + wv * 64;    // wave's output-col base
  const int k0    = blockIdx.y * KPB;

  // ---- stage x fragments once: 1024 octets, 256 threads x 4 ----
#pragma unroll
  for (int i = 0; i < 4; ++i) {
    const int o   = i * 256 + tid;
    const int t   = o >> 7;
    const int m   = (o >> 6) & 1;
    const int ln  = o & 63;
    const int row = m * 16 + (ln & 15);
    const int kof = t * 32 + (ln >> 4) * 8;
    short8 v = cvt8(x + (size_t)row * IN_DIM + k0 + kof);
    *reinterpret_cast<short8*>(&xl[t][m][ln * 8]) = v;
  }
  __syncthreads();

  f32x4 acc[2][4];
#pragma unroll
  for (int m = 0; m < 2; ++m)
#pragma unroll
    for (int n = 0; n < 4; ++n)
      acc[m][n] = (f32x4){0.f, 0.f, 0.f, 0.f};

  const float* wbase = w + (size_t)(ow + l15) * IN_DIM + k0 + lg * 8;

#pragma unroll 2
  for (int t = 0; t < KPB / 32; ++t) {
    const int kk = t * 32;
    short8 aa[2], bb[4];
    aa[0] = *reinterpret_cast<const short8*>(&xl[t][0][lane * 8]);
    aa[1] = *reinterpret_cast<const short8*>(&xl[t][1][lane * 8]);
#pragma unroll
    for (int n = 0; n < 4; ++n)
      bb[n] = cvt8(wbase + (size_t)n * 16 * IN_DIM + kk);
#pragma unroll
    for (int m = 0; m < 2; ++m)
#pragma unroll
      for (int n = 0; n < 4; ++n)
        acc[m][n] = __builtin_amdgcn_mfma_f32_16x16x32_bf16(aa[m], bb[n], acc[m][n], 0, 0, 0);
  }

  // ---- partial store (bf16): ws[blockIdx.y][b][o] ----
  unsigned short* out = ws + (size_t)blockIdx.y * PART_ELEMS;
#pragma unroll
  for (int m = 0; m < 2; ++m)
#pragma unroll
    for (int n = 0; n < 4; ++n)
#pragma unroll
      for (int r = 0; r < 4; ++r) {
        const int brow = m * 16 + lg * 4 + r;   // C/D: row = (lane>>4)*4 + reg
        const int o    = ow + n * 16 + l15;     // col = lane&15
        __hip_bfloat16 h = __float2bfloat16(acc[m][n][r]);
        out[(size_t)brow * OUT_DIM + o] = *reinterpret_cast<unsigned short*>(&h);
      }

  // ---- split-K semaphore: last block for this N-tile reduces ----
  __threadfence();          // release: partials visible device-wide
  __syncthreads();          // all threads' stores issued & fenced
  if (tid == 0) sOld = atomicAdd(&cnt[blockIdx.x], 1u);
  __syncthreads();
  if (sOld != KSPL - 1) return;
  __threadfence();          // acquire: observe other blocks' partials

  const float sc = scale[0];
  const int col8 = (tid & 31) * 8;       // 8 consecutive cols
#pragma unroll
  for (int j = 0; j < 4; ++j) {
    const int row = (tid >> 5) + j * 8;  // 0..31
    const size_t off = (size_t)row * OUT_DIM + obase + col8;
    float s[8] = {0.f, 0.f, 0.f, 0.f, 0.f, 0.f, 0.f, 0.f};
#pragma unroll
    for (int i = 0; i < KSPL; ++i) {
      short8 v = *reinterpret_cast<const short8*>(ws + (size_t)i * PART_ELEMS + off);
#pragma unroll
      for (int e = 0; e < 8; ++e) {
        const unsigned int u = ((unsigned int)(unsigned short)v[e]) << 16;
        s[e] += __uint_as_float(u);
      }
    }
    f32x4 o0 = (f32x4){s[0] * sc, s[1] * sc, s[2] * sc, s[3] * sc};
    f32x4 o1 = (f32x4){s[4] * sc, s[5] * sc, s[6] * sc, s[7] * sc};
    *reinterpret_cast<f32x4*>(y + off)     = o0;
    *reinterpret_cast<f32x4*>(y + off + 4) = o1;
  }
}

extern "C" void kernel_launch(void* const* d_in, const int* in_sizes, int n_in,
                              void* d_out, int out_size, void* d_ws, size_t ws_size,
                              hipStream_t stream) {
  const float* x = (const float*)d_in[0];
  const float* w = (const float*)d_in[1];
  const float* s = (const float*)d_in[2];
  float* y = (float*)d_out;
  unsigned short* ws = (unsigned short*)d_ws;              // 11.27 MB partials
  unsigned int* cnt  = (unsigned int*)((char*)d_ws + CNT_OFF);  // 43 counters

  hipMemsetAsync(cnt, 0, NTILES * sizeof(unsigned int), stream);
  dim3 grid(NTILES, KSPL);   // 43 x 16 = 688 blocks, all co-resident
  bitnet_fused<<<grid, 256, 0, stream>>>(x, w, s, ws, cnt, y);
}

// Round 11
// 54.934 us; speedup vs baseline: 2.8259x; 2.8259x over previous
//
#include <hip/hip_runtime.h>
#include <hip/hip_bf16.h>

typedef __attribute__((ext_vector_type(8))) short short8;
typedef __attribute__((ext_vector_type(4))) float f32x4;

#define OUT_DIM 11008
#define IN_DIM  4096
#define B_DIM   32
#define KSPL    16
#define KPB     (IN_DIM / KSPL)        // 256 k per split-K block
#define PART_ELEMS (B_DIM * OUT_DIM)   // 352256 elems per partial slice

__device__ __forceinline__ short8 cvt8nt(const float* __restrict__ src) {
  // non-temporal: W is read exactly once, keep it out of the caches
  f32x4 f0 = __builtin_nontemporal_load(reinterpret_cast<const f32x4*>(src));
  f32x4 f1 = __builtin_nontemporal_load(reinterpret_cast<const f32x4*>(src) + 1);
  short8 v;
  __hip_bfloat16 h;
  h = __float2bfloat16(f0[0]); v[0] = *reinterpret_cast<short*>(&h);
  h = __float2bfloat16(f0[1]); v[1] = *reinterpret_cast<short*>(&h);
  h = __float2bfloat16(f0[2]); v[2] = *reinterpret_cast<short*>(&h);
  h = __float2bfloat16(f0[3]); v[3] = *reinterpret_cast<short*>(&h);
  h = __float2bfloat16(f1[0]); v[4] = *reinterpret_cast<short*>(&h);
  h = __float2bfloat16(f1[1]); v[5] = *reinterpret_cast<short*>(&h);
  h = __float2bfloat16(f1[2]); v[6] = *reinterpret_cast<short*>(&h);
  h = __float2bfloat16(f1[3]); v[7] = *reinterpret_cast<short*>(&h);
  return v;
}

__device__ __forceinline__ short8 cvt8(const float* __restrict__ src) {
  f32x4 f0 = *reinterpret_cast<const f32x4*>(src);
  f32x4 f1 = *reinterpret_cast<const f32x4*>(src + 4);
  short8 v;
  __hip_bfloat16 h;
  h = __float2bfloat16(f0[0]); v[0] = *reinterpret_cast<short*>(&h);
  h = __float2bfloat16(f0[1]); v[1] = *reinterpret_cast<short*>(&h);
  h = __float2bfloat16(f0[2]); v[2] = *reinterpret_cast<short*>(&h);
  h = __float2bfloat16(f0[3]); v[3] = *reinterpret_cast<short*>(&h);
  h = __float2bfloat16(f1[0]); v[4] = *reinterpret_cast<short*>(&h);
  h = __float2bfloat16(f1[1]); v[5] = *reinterpret_cast<short*>(&h);
  h = __float2bfloat16(f1[2]); v[6] = *reinterpret_cast<short*>(&h);
  h = __float2bfloat16(f1[3]); v[7] = *reinterpret_cast<short*>(&h);
  return v;
}

// R9 structure byte-identical (39.85us best). ONE change: non-temporal
// qualifiers on the streaming traffic (W loads, partial stores/loads).
__global__ __launch_bounds__(256, 4)
void bitnet_partial(const float* __restrict__ x,
                    const float* __restrict__ w,
                    unsigned short* __restrict__ ws)
{
  __shared__ short xl[8][2][64 * 8];   // 16 KB: bf16 A-fragments, staged once

  const int tid  = threadIdx.x;
  const int lane = tid & 63;
  const int wv   = tid >> 6;       // wave 0..3
  const int l15  = lane & 15;
  const int lg   = lane >> 4;      // 0..3
  const int ow   = blockIdx.x * 256 + wv * 64;   // wave's output-col base
  const int k0   = blockIdx.y * KPB;

  // ---- stage x fragments once: 1024 octets, 256 threads x 4 (cached: reused) ----
#pragma unroll
  for (int i = 0; i < 4; ++i) {
    const int o   = i * 256 + tid;
    const int t   = o >> 7;
    const int m   = (o >> 6) & 1;
    const int ln  = o & 63;
    const int row = m * 16 + (ln & 15);
    const int kof = t * 32 + (ln >> 4) * 8;
    short8 v = cvt8(x + (size_t)row * IN_DIM + k0 + kof);
    *reinterpret_cast<short8*>(&xl[t][m][ln * 8]) = v;
  }
  __syncthreads();

  f32x4 acc[2][4];
#pragma unroll
  for (int m = 0; m < 2; ++m)
#pragma unroll
    for (int n = 0; n < 4; ++n)
      acc[m][n] = (f32x4){0.f, 0.f, 0.f, 0.f};

  const float* wbase = w + (size_t)(ow + l15) * IN_DIM + k0 + lg * 8;

#pragma unroll 2
  for (int t = 0; t < KPB / 32; ++t) {
    const int kk = t * 32;
    short8 aa[2], bb[4];
    aa[0] = *reinterpret_cast<const short8*>(&xl[t][0][lane * 8]);
    aa[1] = *reinterpret_cast<const short8*>(&xl[t][1][lane * 8]);
#pragma unroll
    for (int n = 0; n < 4; ++n)
      bb[n] = cvt8nt(wbase + (size_t)n * 16 * IN_DIM + kk);
#pragma unroll
    for (int m = 0; m < 2; ++m)
#pragma unroll
      for (int n = 0; n < 4; ++n)
        acc[m][n] = __builtin_amdgcn_mfma_f32_16x16x32_bf16(aa[m], bb[n], acc[m][n], 0, 0, 0);
  }

  // partial store (bf16, non-temporal): ws[blockIdx.y][b][o]
  unsigned short* out = ws + (size_t)blockIdx.y * PART_ELEMS;
#pragma unroll
  for (int m = 0; m < 2; ++m)
#pragma unroll
    for (int n = 0; n < 4; ++n)
#pragma unroll
      for (int r = 0; r < 4; ++r) {
        const int brow = m * 16 + lg * 4 + r;   // C/D: row = (lane>>4)*4 + reg
        const int o    = ow + n * 16 + l15;     // col = lane&15
        __hip_bfloat16 h = __float2bfloat16(acc[m][n][r]);
        __builtin_nontemporal_store(*reinterpret_cast<unsigned short*>(&h),
                                    &out[(size_t)brow * OUT_DIM + o]);
      }
}

// y[b][o] = scale * sum_{s<16} bf16 ws[s][b][o]; 8 outputs/thread, short8 loads
__global__ __launch_bounds__(256)
void bitnet_reduce(const unsigned short* __restrict__ ws,
                   const float* __restrict__ scale,
                   float* __restrict__ y)
{
  const size_t base = ((size_t)blockIdx.x * 256 + threadIdx.x) * 8;
  float s[8] = {0.f, 0.f, 0.f, 0.f, 0.f, 0.f, 0.f, 0.f};
#pragma unroll
  for (int i = 0; i < KSPL; ++i) {
    short8 v = __builtin_nontemporal_load(
        reinterpret_cast<const short8*>(ws + (size_t)i * PART_ELEMS + base));
#pragma unroll
    for (int j = 0; j < 8; ++j) {
      const unsigned int u = ((unsigned int)(unsigned short)v[j]) << 16;
      s[j] += __uint_as_float(u);
    }
  }
  const float sc = scale[0];
  f32x4 o0 = (f32x4){s[0] * sc, s[1] * sc, s[2] * sc, s[3] * sc};
  f32x4 o1 = (f32x4){s[4] * sc, s[5] * sc, s[6] * sc, s[7] * sc};
  *reinterpret_cast<f32x4*>(y + base)     = o0;
  *reinterpret_cast<f32x4*>(y + base + 4) = o1;
}

extern "C" void kernel_launch(void* const* d_in, const int* in_sizes, int n_in,
                              void* d_out, int out_size, void* d_ws, size_t ws_size,
                              hipStream_t stream) {
  const float* x = (const float*)d_in[0];
  const float* w = (const float*)d_in[1];
  const float* s = (const float*)d_in[2];
  float* y = (float*)d_out;
  unsigned short* ws = (unsigned short*)d_ws;   // KSPL*PART_ELEMS*2 = 11.27 MB

  dim3 grid(OUT_DIM / 256, KSPL);   // 43 x 16 = 688 blocks, fully resident
  bitnet_partial<<<grid, 256, 0, stream>>>(x, w, ws);
  bitnet_reduce<<<PART_ELEMS / 2048, 256, 0, stream>>>(ws, s, y);
}

// Round 12
// 39.816 us; speedup vs baseline: 3.8988x; 1.3797x over previous
//
#include <hip/hip_runtime.h>
#include <hip/hip_bf16.h>

typedef __attribute__((ext_vector_type(8))) short short8;
typedef __attribute__((ext_vector_type(4))) float f32x4;

#define OUT_DIM 11008
#define IN_DIM  4096
#define B_DIM   32
#define KSPL    16
#define KPB     (IN_DIM / KSPL)        // 256 k per split-K block
#define PART_ELEMS (B_DIM * OUT_DIM)   // 352256 elems per partial slice

__device__ __forceinline__ short8 cvt8(const float* __restrict__ src) {
  f32x4 f0 = *reinterpret_cast<const f32x4*>(src);
  f32x4 f1 = *reinterpret_cast<const f32x4*>(src + 4);
  short8 v;
  __hip_bfloat16 h;
  h = __float2bfloat16(f0[0]); v[0] = *reinterpret_cast<short*>(&h);
  h = __float2bfloat16(f0[1]); v[1] = *reinterpret_cast<short*>(&h);
  h = __float2bfloat16(f0[2]); v[2] = *reinterpret_cast<short*>(&h);
  h = __float2bfloat16(f0[3]); v[3] = *reinterpret_cast<short*>(&h);
  h = __float2bfloat16(f1[0]); v[4] = *reinterpret_cast<short*>(&h);
  h = __float2bfloat16(f1[1]); v[5] = *reinterpret_cast<short*>(&h);
  h = __float2bfloat16(f1[2]); v[6] = *reinterpret_cast<short*>(&h);
  h = __float2bfloat16(f1[3]); v[7] = *reinterpret_cast<short*>(&h);
  return v;
}

// Best configuration (R9, 39.85us): direct-from-global W fragments (16 rows x
// 128B cache lines per frag), x staged once in LDS as bf16 A-fragments,
// split-K 16x with bf16 partials in ws + separate reduce kernel.
__global__ __launch_bounds__(256, 4)
void bitnet_partial(const float* __restrict__ x,
                    const float* __restrict__ w,
                    unsigned short* __restrict__ ws)
{
  __shared__ short xl[8][2][64 * 8];   // 16 KB: bf16 A-fragments, staged once

  const int tid  = threadIdx.x;
  const int lane = tid & 63;
  const int wv   = tid >> 6;       // wave 0..3
  const int l15  = lane & 15;
  const int lg   = lane >> 4;      // 0..3
  const int ow   = blockIdx.x * 256 + wv * 64;   // wave's output-col base
  const int k0   = blockIdx.y * KPB;

  // ---- stage x fragments once: 1024 octets, 256 threads x 4 ----
#pragma unroll
  for (int i = 0; i < 4; ++i) {
    const int o   = i * 256 + tid;
    const int t   = o >> 7;
    const int m   = (o >> 6) & 1;
    const int ln  = o & 63;
    const int row = m * 16 + (ln & 15);
    const int kof = t * 32 + (ln >> 4) * 8;
    short8 v = cvt8(x + (size_t)row * IN_DIM + k0 + kof);
    *reinterpret_cast<short8*>(&xl[t][m][ln * 8]) = v;
  }
  __syncthreads();

  f32x4 acc[2][4];
#pragma unroll
  for (int m = 0; m < 2; ++m)
#pragma unroll
    for (int n = 0; n < 4; ++n)
      acc[m][n] = (f32x4){0.f, 0.f, 0.f, 0.f};

  const float* wbase = w + (size_t)(ow + l15) * IN_DIM + k0 + lg * 8;

#pragma unroll 2
  for (int t = 0; t < KPB / 32; ++t) {
    const int kk = t * 32;
    short8 aa[2], bb[4];
    aa[0] = *reinterpret_cast<const short8*>(&xl[t][0][lane * 8]);
    aa[1] = *reinterpret_cast<const short8*>(&xl[t][1][lane * 8]);
#pragma unroll
    for (int n = 0; n < 4; ++n)
      bb[n] = cvt8(wbase + (size_t)n * 16 * IN_DIM + kk);
#pragma unroll
    for (int m = 0; m < 2; ++m)
#pragma unroll
      for (int n = 0; n < 4; ++n)
        acc[m][n] = __builtin_amdgcn_mfma_f32_16x16x32_bf16(aa[m], bb[n], acc[m][n], 0, 0, 0);
  }

  // partial store (bf16): ws[blockIdx.y][b][o]
  unsigned short* out = ws + (size_t)blockIdx.y * PART_ELEMS;
#pragma unroll
  for (int m = 0; m < 2; ++m)
#pragma unroll
    for (int n = 0; n < 4; ++n)
#pragma unroll
      for (int r = 0; r < 4; ++r) {
        const int brow = m * 16 + lg * 4 + r;   // C/D: row = (lane>>4)*4 + reg
        const int o    = ow + n * 16 + l15;     // col = lane&15
        __hip_bfloat16 h = __float2bfloat16(acc[m][n][r]);
        out[(size_t)brow * OUT_DIM + o] = *reinterpret_cast<unsigned short*>(&h);
      }
}

// y[b][o] = scale * sum_{s<16} bf16 ws[s][b][o]; 8 outputs/thread, short8 loads
__global__ __launch_bounds__(256)
void bitnet_reduce(const unsigned short* __restrict__ ws,
                   const float* __restrict__ scale,
                   float* __restrict__ y)
{
  const size_t base = ((size_t)blockIdx.x * 256 + threadIdx.x) * 8;
  float s[8] = {0.f, 0.f, 0.f, 0.f, 0.f, 0.f, 0.f, 0.f};
#pragma unroll
  for (int i = 0; i < KSPL; ++i) {
    short8 v = *reinterpret_cast<const short8*>(ws + (size_t)i * PART_ELEMS + base);
#pragma unroll
    for (int j = 0; j < 8; ++j) {
      const unsigned int u = ((unsigned int)(unsigned short)v[j]) << 16;
      s[j] += __uint_as_float(u);
    }
  }
  const float sc = scale[0];
  f32x4 o0 = (f32x4){s[0] * sc, s[1] * sc, s[2] * sc, s[3] * sc};
  f32x4 o1 = (f32x4){s[4] * sc, s[5] * sc, s[6] * sc, s[7] * sc};
  *reinterpret_cast<f32x4*>(y + base)     = o0;
  *reinterpret_cast<f32x4*>(y + base + 4) = o1;
}

extern "C" void kernel_launch(void* const* d_in, const int* in_sizes, int n_in,
                              void* d_out, int out_size, void* d_ws, size_t ws_size,
                              hipStream_t stream) {
  const float* x = (const float*)d_in[0];
  const float* w = (const float*)d_in[1];
  const float* s = (const float*)d_in[2];
  float* y = (float*)d_out;
  unsigned short* ws = (unsigned short*)d_ws;   // KSPL*PART_ELEMS*2 = 11.27 MB

  dim3 grid(OUT_DIM / 256, KSPL);   // 43 x 16 = 688 blocks, fully resident
  bitnet_partial<<<grid, 256, 0, stream>>>(x, w, ws);
  bitnet_reduce<<<PART_ELEMS / 2048, 256, 0, stream>>>(ws, s, y);
}